// Round 5
// baseline (371.586 us; speedup 1.0000x reference)
//
#include <hip/hip_runtime.h>

#define B_  2
#define C_  192
#define L_  4096
#define NH_ 8
#define HD_ 24
#define C3_ 576
#define KV_ 64
#define NT_ (L_ / KV_)

typedef _Float16 f16;
typedef __attribute__((ext_vector_type(8))) f16 f16x8;
typedef __attribute__((ext_vector_type(16))) float f32x16;

#define L2E_ 1.4426950408889634f

__device__ __forceinline__ int pk2(float a, float b) {
    union { __fp16 h __attribute__((ext_vector_type(2))); int i; } u;
    u.h = __builtin_amdgcn_cvt_pkrtz(a, b);
    return u.i;
}
__device__ __forceinline__ int pk2_rte(float a, float b) {
    union { f16 h[2]; int i; } u;
    u.h[0] = (f16)a; u.h[1] = (f16)b;
    return u.i;
}
// bare hardware 2^x
__device__ __forceinline__ float ex2(float x) {
    float r;
    asm("v_exp_f32 %0, %1" : "=v"(r) : "v"(x));
    return r;
}

union Frag { f16x8 v; int i[4]; };

#define MFMA32(A, Bx, Cc) __builtin_amdgcn_mfma_f32_32x32x16_f16((A), (Bx), (Cc), 0, 0, 0)

// async global -> LDS, 4B per lane; LDS dest = wave-uniform base + lane*4
__device__ __forceinline__ void gload4(const void* g, void* lds) {
    typedef const unsigned int __attribute__((address_space(1))) as1u;
    typedef unsigned int __attribute__((address_space(3))) as3u;
    __builtin_amdgcn_global_load_lds((as1u*)g,
                                     (as3u*)(unsigned int)(unsigned long long)lds,
                                     4, 0, 0);
}

#define WAITV(N) asm volatile("s_waitcnt vmcnt(" #N ")" ::: "memory")
#define BAR()    __builtin_amdgcn_s_barrier()

// ---------------------------------------------------------------------------
// QKV 1x1 conv -> packed f16 workspace.
// Q,K: half2 pair-words q2/k2[b][h][dp=0..11][L]  (Q pre-scaled by 8^-0.5 * log2e)
// V:   plain f16        v16[b][h][d=0..23][L]
// ---------------------------------------------------------------------------
__global__ __launch_bounds__(256) void lin_qkv(const float* __restrict__ a,
                                               const float* __restrict__ w,
                                               const float* __restrict__ bias,
                                               unsigned int* __restrict__ q2,
                                               unsigned int* __restrict__ k2,
                                               unsigned short* __restrict__ v16) {
    __shared__ float wl[8][C_];
    const int og  = blockIdx.x;          // 0..71 (8 out-channels each)
    const int b   = blockIdx.y >> 4;
    const int lt  = blockIdx.y & 15;
    const int tid = threadIdx.x;

    for (int e = tid; e < 8 * C_; e += 256) wl[e / C_][e % C_] = w[og * 8 * C_ + e];
    __syncthreads();

    const int l = lt * 256 + tid;
    float acc[8];
#pragma unroll
    for (int j = 0; j < 8; ++j) acc[j] = bias[og * 8 + j];

    const float* ap = a + (size_t)b * C_ * L_ + l;
#pragma unroll 2
    for (int c = 0; c < C_; ++c) {
        const float xv = ap[(size_t)c * L_];
#pragma unroll
        for (int j = 0; j < 8; ++j) acc[j] = fmaf(wl[j][c], xv, acc[j]);
    }

    const float qscale = 0.35355339059327373f * L2E_;  // heads^-0.5 * log2e
    if (og < 48) {
        unsigned int* dst = (og < 24) ? q2 : k2;
        const int og_ = (og < 24) ? og : og - 24;
        const float sc = (og < 24) ? qscale : 1.f;
        const int h = og_ / 3, j0 = (og_ % 3) * 4;
        unsigned int* p = dst + ((size_t)(b * NH_ + h) * 12 + j0) * L_ + l;
#pragma unroll
        for (int j = 0; j < 4; ++j)
            p[(size_t)j * L_] = pk2_rte(acc[2 * j] * sc, acc[2 * j + 1] * sc);
    } else {
        const int og_ = og - 48;
        const int h = og_ / 3, d0 = (og_ % 3) * 8;
        unsigned short* p = v16 + ((size_t)(b * NH_ + h) * 24 + d0) * L_ + l;
#pragma unroll
        for (int j = 0; j < 8; ++j) {
            union { f16 hf; unsigned short us; } cv;
            cv.hf = (f16)acc[j];
            p[(size_t)j * L_] = cv.us;
        }
    }
}

// ---------------------------------------------------------------------------
// f32 per-pixel linear (output projection)
// ---------------------------------------------------------------------------
__global__ __launch_bounds__(256) void lin_kernel(const float* __restrict__ a,
                                                  const float* __restrict__ w,
                                                  const float* __restrict__ bias,
                                                  float* __restrict__ out, int OC) {
    __shared__ float wl[8][C_];
    const int og  = blockIdx.x;
    const int b   = blockIdx.y >> 4;
    const int lt  = blockIdx.y & 15;
    const int tid = threadIdx.x;

    for (int e = tid; e < 8 * C_; e += 256) wl[e / C_][e % C_] = w[og * 8 * C_ + e];
    __syncthreads();

    const int l = lt * 256 + tid;
    float acc[8];
#pragma unroll
    for (int j = 0; j < 8; ++j) acc[j] = bias[og * 8 + j];

    const float* ap = a + (size_t)b * C_ * L_ + l;
#pragma unroll 2
    for (int c = 0; c < C_; ++c) {
        const float xv = ap[(size_t)c * L_];
#pragma unroll
        for (int j = 0; j < 8; ++j) acc[j] = fmaf(wl[j][c], xv, acc[j]);
    }

    float* op = out + ((size_t)b * OC + og * 8) * L_ + l;
#pragma unroll
    for (int j = 0; j < 8; ++j) op[(size_t)j * L_] = acc[j];
}

// ---------------------------------------------------------------------------
// MFMA f16 flash attention, T3/T4 pipeline:
// 4-deep LDS ring, K/V staged 2 tiles ahead (gload_lds), mask regs 1 ahead,
// counted s_waitcnt vmcnt(20) + raw s_barrier (ONE per tile, never drain).
// Softmax in log2 domain (Q pre-scaled by log2e, mask*log2e at C-init).
// grid flat 512: bid = h*64 + b*32 + qt  (8 heads of a qtile share bid%8 = XCD)
// ---------------------------------------------------------------------------
__global__ __launch_bounds__(256) void attn_mfma(const unsigned int* __restrict__ q2,
                                                 const unsigned int* __restrict__ k2,
                                                 const unsigned short* __restrict__ v16,
                                                 const float* __restrict__ mask,
                                                 float* __restrict__ out) {
    const int tid  = threadIdx.x;
    const int lane = tid & 63;
    const int wid  = tid >> 6;
    const int hi   = lane >> 5;
    const int lq   = lane & 31;
    const int bid  = blockIdx.x;
    const int h    = bid >> 6;
    const int b    = (bid >> 5) & 1;
    const int qt   = bid & 31;
    const int qrow = qt * 128 + wid * 32 + lq;

    __shared__ int k_lds[4][16][64];   // rows 12..15 zeroed (pad; Q-side is zero there too,
    __shared__ int v_lds[4][32][32];   //  but NaN garbage * 0 = NaN, so zero them)
                                       // v rows 24..31 garbage -> only feeds dropped O rows

    // every wave zeroes ALL pad rows (benign same-value race; no barrier needed)
#pragma unroll
    for (int bf = 0; bf < 4; ++bf)
#pragma unroll
        for (int i = 0; i < 4; ++i) k_lds[bf][12 + i][lane] = 0;

    const unsigned int*   qb = q2  + (size_t)(b * NH_ + h) * 12 * L_;
    const unsigned int*   kb = k2  + (size_t)(b * NH_ + h) * 12 * L_;
    const unsigned short* vb = v16 + (size_t)(b * NH_ + h) * 24 * L_;
    const float* mrow = mask + ((size_t)b * L_ + qrow) * L_;

    // Q fragments (pair-words; zero where dpq >= 12 -> K pad contributes 0)
    int bq[8];
#pragma unroll
    for (int s = 0; s < 2; ++s)
#pragma unroll
        for (int t = 0; t < 4; ++t) {
            const int dpq = 8 * s + 4 * hi + t;
            bq[s * 4 + t] = (dpq < 12) ? qb[(size_t)dpq * L_ + qrow] : 0;
        }

    // staging sources; LDS word offsets wave-uniform-base + lane
    const unsigned int*   kg[3];
    const unsigned short* vg[3];
    int ls_off[3];
#pragma unroll
    for (int i = 0; i < 3; ++i) {
        const int e = i * 256 + tid;
        kg[i]     = kb + (size_t)(e >> 6) * L_ + (e & 63);
        const int d = e >> 5, slot = e & 31;
        vg[i]     = vb + (size_t)d * L_ + 2 * (slot ^ d);   // XOR pre-swizzled source
        ls_off[i] = i * 256 + 64 * wid;
    }

#define STAGE(BF, KK) do {                                                    \
    _Pragma("unroll")                                                         \
    for (int i_ = 0; i_ < 3; ++i_) {                                          \
        gload4(kg[i_] + (KK), &k_lds[BF][0][0] + ls_off[i_]);                 \
        gload4(vg[i_] + (KK), &v_lds[BF][0][0] + ls_off[i_]);                 \
    } } while (0)

#define MLOAD(MD, KK) do {                                                    \
    const float4* mb_ = (const float4*)(mrow + (KK));                         \
    _Pragma("unroll")                                                         \
    for (int u_ = 0; u_ < 2; ++u_)                                            \
        _Pragma("unroll")                                                     \
        for (int q_ = 0; q_ < 4; ++q_)                                        \
            MD[u_ * 4 + q_] = mb_[8 * u_ + 2 * q_ + hi];                      \
    } while (0)

#define PVSTEP(BF, CU, U) do {                                                \
    int w1[4], w2[4], s1[4], s2[4];                                           \
    _Pragma("unroll")                                                         \
    for (int q_ = 0; q_ < 4; ++q_) {                                          \
        w1[q_] = pk2(CU[4 * q_], CU[4 * q_ + 1]);                             \
        w2[q_] = pk2(CU[4 * q_ + 2], CU[4 * q_ + 3]);                         \
    }                                                                         \
    _Pragma("unroll")                                                         \
    for (int q_ = 0; q_ < 4; ++q_) {                                          \
        s1[q_] = __shfl_xor(w1[q_], 32);                                      \
        s2[q_] = __shfl_xor(w2[q_], 32);                                      \
    }                                                                         \
    _Pragma("unroll")                                                         \
    for (int s_ = 0; s_ < 2; ++s_) {                                          \
        const int qq_ = 2 * s_ + hi;                                          \
        Frag pb, va;                                                          \
        pb.i[0] = hi ? s1[qq_] : w1[qq_];                                     \
        pb.i[1] = hi ? s2[qq_] : w2[qq_];                                     \
        pb.i[2] = hi ? w1[qq_] : s1[qq_];                                     \
        pb.i[3] = hi ? w2[qq_] : s2[qq_];                                     \
        _Pragma("unroll")                                                     \
        for (int t_ = 0; t_ < 4; ++t_)                                        \
            va.i[t_] = v_lds[BF][lq][(16 * U + 8 * s_ + 4 * hi + t_) ^ lq];   \
        __builtin_amdgcn_s_setprio(1);                                        \
        o = MFMA32(va.v, pb.v, o);                                            \
        __builtin_amdgcn_s_setprio(0);                                        \
    } } while (0)

#define COMPUTE(BF, MC) do {                                                  \
    f32x16 c0, c1;                                                            \
    c0[0]  = MC[0].x * L2E_; c0[1]  = MC[0].y * L2E_;                         \
    c0[2]  = MC[0].z * L2E_; c0[3]  = MC[0].w * L2E_;                         \
    c0[4]  = MC[1].x * L2E_; c0[5]  = MC[1].y * L2E_;                         \
    c0[6]  = MC[1].z * L2E_; c0[7]  = MC[1].w * L2E_;                         \
    c0[8]  = MC[2].x * L2E_; c0[9]  = MC[2].y * L2E_;                         \
    c0[10] = MC[2].z * L2E_; c0[11] = MC[2].w * L2E_;                         \
    c0[12] = MC[3].x * L2E_; c0[13] = MC[3].y * L2E_;                         \
    c0[14] = MC[3].z * L2E_; c0[15] = MC[3].w * L2E_;                         \
    c1[0]  = MC[4].x * L2E_; c1[1]  = MC[4].y * L2E_;                         \
    c1[2]  = MC[4].z * L2E_; c1[3]  = MC[4].w * L2E_;                         \
    c1[4]  = MC[5].x * L2E_; c1[5]  = MC[5].y * L2E_;                         \
    c1[6]  = MC[5].z * L2E_; c1[7]  = MC[5].w * L2E_;                         \
    c1[8]  = MC[6].x * L2E_; c1[9]  = MC[6].y * L2E_;                         \
    c1[10] = MC[6].z * L2E_; c1[11] = MC[6].w * L2E_;                         \
    c1[12] = MC[7].x * L2E_; c1[13] = MC[7].y * L2E_;                         \
    c1[14] = MC[7].z * L2E_; c1[15] = MC[7].w * L2E_;                         \
    Frag qf0, qf1, ka0, ka1;                                                  \
    _Pragma("unroll")                                                         \
    for (int t_ = 0; t_ < 4; ++t_) { qf0.i[t_] = bq[t_]; qf1.i[t_] = bq[4 + t_]; } \
    _Pragma("unroll")                                                         \
    for (int t_ = 0; t_ < 4; ++t_) {                                          \
        ka0.i[t_] = k_lds[BF][4 * hi + t_][lq];                               \
        ka1.i[t_] = k_lds[BF][8 + 4 * hi + t_][lq];                           \
    }                                                                         \
    __builtin_amdgcn_s_setprio(1);                                            \
    c0 = MFMA32(ka0.v, qf0.v, c0);                                            \
    c0 = MFMA32(ka1.v, qf1.v, c0);                                            \
    __builtin_amdgcn_s_setprio(0);                                            \
    _Pragma("unroll")                                                         \
    for (int t_ = 0; t_ < 4; ++t_) {                                          \
        ka0.i[t_] = k_lds[BF][4 * hi + t_][32 + lq];                          \
        ka1.i[t_] = k_lds[BF][8 + 4 * hi + t_][32 + lq];                      \
    }                                                                         \
    __builtin_amdgcn_s_setprio(1);                                            \
    c1 = MFMA32(ka0.v, qf0.v, c1);                                            \
    c1 = MFMA32(ka1.v, qf1.v, c1);                                            \
    __builtin_amdgcn_s_setprio(0);                                            \
    float pmax = c0[0];                                                       \
    _Pragma("unroll")                                                         \
    for (int i_ = 1; i_ < 16; ++i_) pmax = fmaxf(pmax, c0[i_]);               \
    _Pragma("unroll")                                                         \
    for (int i_ = 0; i_ < 16; ++i_) pmax = fmaxf(pmax, c1[i_]);               \
    pmax = fmaxf(pmax, __shfl_xor(pmax, 32));                                 \
    if (!__all((int)(pmax <= mrun + 11.5415603f))) {                          \
        const float newm_ = fmaxf(mrun, pmax);                                \
        const float r_ = ex2(mrun - newm_);                                   \
        srun *= r_;                                                           \
        _Pragma("unroll")                                                     \
        for (int i_ = 0; i_ < 16; ++i_) o[i_] *= r_;                          \
        mrun = newm_;                                                         \
    }                                                                         \
    float ls = 0.f;                                                           \
    _Pragma("unroll")                                                         \
    for (int i_ = 0; i_ < 16; ++i_) { c0[i_] = ex2(c0[i_] - mrun); ls += c0[i_]; } \
    _Pragma("unroll")                                                         \
    for (int i_ = 0; i_ < 16; ++i_) { c1[i_] = ex2(c1[i_] - mrun); ls += c1[i_]; } \
    ls += __shfl_xor(ls, 32);                                                 \
    srun += ls;                                                               \
    PVSTEP(BF, c0, 0);                                                        \
    PVSTEP(BF, c1, 1);                                                        \
    } while (0)

    f32x16 o;
#pragma unroll
    for (int i = 0; i < 16; ++i) o[i] = 0.f;
    float mrun = -1e30f, srun = 0.f;
    float4 ma[8], mb[8];

    // prologue: tiles 0,1 K/V staged; mask(0) in regs  (20 vm ops in flight)
    STAGE(0, 0);
    MLOAD(ma, 0);
    STAGE(1, KV_);

#pragma clang loop unroll(disable)
    for (int t = 0; t < NT_ - 4; t += 4) {
        const int kk = t * KV_;
        MLOAD(mb, kk + 1 * KV_); STAGE(2, kk + 2 * KV_); WAITV(20); BAR(); COMPUTE(0, ma);
        MLOAD(ma, kk + 2 * KV_); STAGE(3, kk + 3 * KV_); WAITV(20); BAR(); COMPUTE(1, mb);
        MLOAD(mb, kk + 3 * KV_); STAGE(0, kk + 4 * KV_); WAITV(20); BAR(); COMPUTE(2, ma);
        MLOAD(ma, kk + 4 * KV_); STAGE(1, kk + 5 * KV_); WAITV(20); BAR(); COMPUTE(3, mb);
    }
    {   // tail: tiles 60..63 (staged through 61, mask(60) in ma)
        const int kk = (NT_ - 4) * KV_;
        MLOAD(mb, kk + 1 * KV_); STAGE(2, kk + 2 * KV_); WAITV(20); BAR(); COMPUTE(0, ma);
        MLOAD(ma, kk + 2 * KV_); STAGE(3, kk + 3 * KV_); WAITV(20); BAR(); COMPUTE(1, mb);
        MLOAD(mb, kk + 3 * KV_);                         WAITV(14); BAR(); COMPUTE(2, ma);
                                                         WAITV(0);  BAR(); COMPUTE(3, mb);
    }

    const float inv = 1.f / srun;
    float* op = out + ((size_t)b * C_ + h * HD_) * L_ + qrow;
#pragma unroll
    for (int i = 0; i < 16; ++i) {
        const int d = (i & 3) + 8 * (i >> 2) + 4 * hi;
        if (d < HD_) op[(size_t)d * L_] = o[i] * inv;
    }
#undef STAGE
#undef MLOAD
#undef PVSTEP
#undef COMPUTE
}

// ---------------------------------------------------------------------------
extern "C" void kernel_launch(void* const* d_in, const int* in_sizes, int n_in,
                              void* d_out, int out_size, void* d_ws, size_t ws_size,
                              hipStream_t stream) {
    const float* x      = (const float*)d_in[0];
    const float* mask   = (const float*)d_in[1];
    const float* w_qkv  = (const float*)d_in[2];
    const float* b_qkv  = (const float*)d_in[3];
    const float* w_proj = (const float*)d_in[4];
    const float* b_proj = (const float*)d_in[5];
    float* out = (float*)d_out;

    unsigned int*   q2  = (unsigned int*)d_ws;                    // B*8*12*L u32
    unsigned int*   k2  = q2 + (size_t)B_ * NH_ * 12 * L_;        // B*8*12*L u32
    unsigned short* v16 = (unsigned short*)(k2 + (size_t)B_ * NH_ * 12 * L_);  // B*8*24*L u16
    float* ws_att = (float*)(v16 + (size_t)B_ * NH_ * 24 * L_);   // B*192*L f32

    lin_qkv<<<dim3(72, 32), 256, 0, stream>>>(x, w_qkv, b_qkv, q2, k2, v16);
    attn_mfma<<<dim3(512), 256, 0, stream>>>(q2, k2, v16, mask, ws_att);
    lin_kernel<<<dim3(24, 32), 256, 0, stream>>>(ws_att, w_proj, b_proj, out, C_);
}

// Round 6
// 345.037 us; speedup vs baseline: 1.0769x; 1.0769x over previous
//
#include <hip/hip_runtime.h>

#define B_  2
#define C_  192
#define L_  4096
#define NH_ 8
#define HD_ 24
#define C3_ 576
#define KV_ 64
#define NSPL_ 2
#define LSPL_ (L_ / NSPL_)
#define NT2_ (LSPL_ / KV_)

typedef _Float16 f16;
typedef __attribute__((ext_vector_type(8))) f16 f16x8;
typedef __attribute__((ext_vector_type(16))) float f32x16;

#define L2E_ 1.4426950408889634f

__device__ __forceinline__ int pk2(float a, float b) {
    union { __fp16 h __attribute__((ext_vector_type(2))); int i; } u;
    u.h = __builtin_amdgcn_cvt_pkrtz(a, b);
    return u.i;
}
__device__ __forceinline__ int pk2_rte(float a, float b) {
    union { f16 h[2]; int i; } u;
    u.h[0] = (f16)a; u.h[1] = (f16)b;
    return u.i;
}
// bare hardware 2^x / log2(x)
__device__ __forceinline__ float ex2(float x) {
    float r;
    asm("v_exp_f32 %0, %1" : "=v"(r) : "v"(x));
    return r;
}
__device__ __forceinline__ float lg2(float x) {
    float r;
    asm("v_log_f32 %0, %1" : "=v"(r) : "v"(x));
    return r;
}

union Frag { f16x8 v; int i[4]; };

#define MFMA32(A, Bx, Cc) __builtin_amdgcn_mfma_f32_32x32x16_f16((A), (Bx), (Cc), 0, 0, 0)

// async global -> LDS, 4B per lane; LDS dest = wave-uniform base + lane*4
__device__ __forceinline__ void gload4(const void* g, void* lds) {
    typedef const unsigned int __attribute__((address_space(1))) as1u;
    typedef unsigned int __attribute__((address_space(3))) as3u;
    __builtin_amdgcn_global_load_lds((as1u*)g,
                                     (as3u*)(unsigned int)(unsigned long long)lds,
                                     4, 0, 0);
}

// ---------------------------------------------------------------------------
// QKV 1x1 conv -> packed f16 workspace.
// Q,K: half2 pair-words q2/k2[b][h][dp=0..11][L]  (Q pre-scaled by 8^-0.5*log2e)
// V:   plain f16        v16[b][h][d=0..23][L]
// ---------------------------------------------------------------------------
__global__ __launch_bounds__(256) void lin_qkv(const float* __restrict__ a,
                                               const float* __restrict__ w,
                                               const float* __restrict__ bias,
                                               unsigned int* __restrict__ q2,
                                               unsigned int* __restrict__ k2,
                                               unsigned short* __restrict__ v16) {
    __shared__ float wl[8][C_];
    const int og  = blockIdx.x;          // 0..71 (8 out-channels each)
    const int b   = blockIdx.y >> 4;
    const int lt  = blockIdx.y & 15;
    const int tid = threadIdx.x;

    for (int e = tid; e < 8 * C_; e += 256) wl[e / C_][e % C_] = w[og * 8 * C_ + e];
    __syncthreads();

    const int l = lt * 256 + tid;
    float acc[8];
#pragma unroll
    for (int j = 0; j < 8; ++j) acc[j] = bias[og * 8 + j];

    const float* ap = a + (size_t)b * C_ * L_ + l;
#pragma unroll 2
    for (int c = 0; c < C_; ++c) {
        const float xv = ap[(size_t)c * L_];
#pragma unroll
        for (int j = 0; j < 8; ++j) acc[j] = fmaf(wl[j][c], xv, acc[j]);
    }

    const float qscale = 0.35355339059327373f * L2E_;  // heads^-0.5 * log2e
    if (og < 48) {
        unsigned int* dst = (og < 24) ? q2 : k2;
        const int og_ = (og < 24) ? og : og - 24;
        const float sc = (og < 24) ? qscale : 1.f;
        const int h = og_ / 3, j0 = (og_ % 3) * 4;
        unsigned int* p = dst + ((size_t)(b * NH_ + h) * 12 + j0) * L_ + l;
#pragma unroll
        for (int j = 0; j < 4; ++j)
            p[(size_t)j * L_] = pk2_rte(acc[2 * j] * sc, acc[2 * j + 1] * sc);
    } else {
        const int og_ = og - 48;
        const int h = og_ / 3, d0 = (og_ % 3) * 8;
        unsigned short* p = v16 + ((size_t)(b * NH_ + h) * 24 + d0) * L_ + l;
#pragma unroll
        for (int j = 0; j < 8; ++j) {
            union { f16 hf; unsigned short us; } cv;
            cv.hf = (f16)acc[j];
            p[(size_t)j * L_] = cv.us;
        }
    }
}

// ---------------------------------------------------------------------------
// f32 per-pixel linear (output projection)
// ---------------------------------------------------------------------------
__global__ __launch_bounds__(256) void lin_kernel(const float* __restrict__ a,
                                                  const float* __restrict__ w,
                                                  const float* __restrict__ bias,
                                                  float* __restrict__ out, int OC) {
    __shared__ float wl[8][C_];
    const int og  = blockIdx.x;
    const int b   = blockIdx.y >> 4;
    const int lt  = blockIdx.y & 15;
    const int tid = threadIdx.x;

    for (int e = tid; e < 8 * C_; e += 256) wl[e / C_][e % C_] = w[og * 8 * C_ + e];
    __syncthreads();

    const int l = lt * 256 + tid;
    float acc[8];
#pragma unroll
    for (int j = 0; j < 8; ++j) acc[j] = bias[og * 8 + j];

    const float* ap = a + (size_t)b * C_ * L_ + l;
#pragma unroll 2
    for (int c = 0; c < C_; ++c) {
        const float xv = ap[(size_t)c * L_];
#pragma unroll
        for (int j = 0; j < 8; ++j) acc[j] = fmaf(wl[j][c], xv, acc[j]);
    }

    float* op = out + ((size_t)b * OC + og * 8) * L_ + l;
#pragma unroll
    for (int j = 0; j < 8; ++j) op[(size_t)j * L_] = acc[j];
}

// ---------------------------------------------------------------------------
// MFMA f16 flash attention, KV-split x2 (flash-decoding).
// grid flat 1024: bid = split*512 + h*64 + b*32 + qt.
// Each block: 32 KV tiles of 64 keys; double-buffered LDS (gload_lds),
// drain barriers (R4 schedule — cross-block TLP at 4 blocks/CU hides them).
// Softmax in log2 domain. Partials: O normalized (f16) + lse (f32).
// ---------------------------------------------------------------------------
__global__ __launch_bounds__(256) void attn_mfma(const unsigned int* __restrict__ q2,
                                                 const unsigned int* __restrict__ k2,
                                                 const unsigned short* __restrict__ v16,
                                                 const float* __restrict__ mask,
                                                 unsigned short* __restrict__ po,
                                                 float* __restrict__ pms) {
    const int tid  = threadIdx.x;
    const int lane = tid & 63;
    const int wid  = tid >> 6;
    const int hi   = lane >> 5;
    const int lq   = lane & 31;
    const int bid  = blockIdx.x;
    const int sp   = bid >> 9;
    const int r    = bid & 511;
    const int h    = r >> 6;
    const int b    = (r >> 5) & 1;
    const int qt   = r & 31;
    const int qrow = qt * 128 + wid * 32 + lq;
    const int kv0  = sp * LSPL_;

    __shared__ int k_lds[2][16][64];   // rows 12..15 zeroed (pad on contraction dim)
    __shared__ int v_lds[2][32][32];   // rows 24..31 garbage -> only dropped O rows

    {   // zero K pad rows (before first barrier)
        const int rr = 12 + (tid >> 6), cc = tid & 63;
        k_lds[0][rr][cc] = 0;
        k_lds[1][rr][cc] = 0;
    }

    const unsigned int*   qb = q2  + (size_t)(b * NH_ + h) * 12 * L_;
    const unsigned int*   kb = k2  + (size_t)(b * NH_ + h) * 12 * L_;
    const unsigned short* vb = v16 + (size_t)(b * NH_ + h) * 24 * L_;
    const float* mrow = mask + ((size_t)b * L_ + qrow) * L_;

    // Q fragments (pair-words; zero where dpq >= 12 -> K pad contributes 0)
    int bq[8];
#pragma unroll
    for (int s = 0; s < 2; ++s)
#pragma unroll
        for (int t = 0; t < 4; ++t) {
            const int dpq = 8 * s + 4 * hi + t;
            bq[s * 4 + t] = (dpq < 12) ? qb[(size_t)dpq * L_ + qrow] : 0;
        }

    // staging sources; LDS word offsets wave-uniform-base (+ lane*4 by HW)
    const unsigned int*   kg[3];
    const unsigned short* vg[3];
    int ls_off[3];
#pragma unroll
    for (int i = 0; i < 3; ++i) {
        const int e = i * 256 + tid;
        kg[i]     = kb + (size_t)(e >> 6) * L_ + (e & 63);
        const int d = e >> 5, slot = e & 31;
        vg[i]     = vb + (size_t)d * L_ + 2 * (slot ^ d);   // XOR pre-swizzled source
        ls_off[i] = i * 256 + 64 * wid;
    }

#define STAGE(BF, KK) do {                                                    \
    _Pragma("unroll")                                                         \
    for (int i_ = 0; i_ < 3; ++i_) {                                          \
        gload4(kg[i_] + (KK), &k_lds[BF][0][0] + ls_off[i_]);                 \
        gload4(vg[i_] + (KK), &v_lds[BF][0][0] + ls_off[i_]);                 \
    } } while (0)

#define MLOAD(MD, KK) do {                                                    \
    const float4* mb_ = (const float4*)(mrow + (KK));                         \
    _Pragma("unroll")                                                         \
    for (int u_ = 0; u_ < 2; ++u_)                                            \
        _Pragma("unroll")                                                     \
        for (int q_ = 0; q_ < 4; ++q_)                                        \
            MD[u_ * 4 + q_] = mb_[8 * u_ + 2 * q_ + hi];                      \
    } while (0)

#define PVSTEP(BF, CU, U) do {                                                \
    int w1[4], w2[4], s1[4], s2[4];                                           \
    _Pragma("unroll")                                                         \
    for (int q_ = 0; q_ < 4; ++q_) {                                          \
        w1[q_] = pk2(CU[4 * q_], CU[4 * q_ + 1]);                             \
        w2[q_] = pk2(CU[4 * q_ + 2], CU[4 * q_ + 3]);                         \
    }                                                                         \
    _Pragma("unroll")                                                         \
    for (int q_ = 0; q_ < 4; ++q_) {                                          \
        s1[q_] = __shfl_xor(w1[q_], 32);                                      \
        s2[q_] = __shfl_xor(w2[q_], 32);                                      \
    }                                                                         \
    _Pragma("unroll")                                                         \
    for (int s_ = 0; s_ < 2; ++s_) {                                          \
        const int qq_ = 2 * s_ + hi;                                          \
        Frag pb, va;                                                          \
        pb.i[0] = hi ? s1[qq_] : w1[qq_];                                     \
        pb.i[1] = hi ? s2[qq_] : w2[qq_];                                     \
        pb.i[2] = hi ? w1[qq_] : s1[qq_];                                     \
        pb.i[3] = hi ? w2[qq_] : s2[qq_];                                     \
        _Pragma("unroll")                                                     \
        for (int t_ = 0; t_ < 4; ++t_)                                        \
            va.i[t_] = v_lds[BF][lq][(16 * U + 8 * s_ + 4 * hi + t_) ^ lq];   \
        __builtin_amdgcn_s_setprio(1);                                        \
        o = MFMA32(va.v, pb.v, o);                                            \
        __builtin_amdgcn_s_setprio(0);                                        \
    } } while (0)

#define COMPUTE(BF, MC) do {                                                  \
    f32x16 c0, c1;                                                            \
    c0[0]  = MC[0].x * L2E_; c0[1]  = MC[0].y * L2E_;                         \
    c0[2]  = MC[0].z * L2E_; c0[3]  = MC[0].w * L2E_;                         \
    c0[4]  = MC[1].x * L2E_; c0[5]  = MC[1].y * L2E_;                         \
    c0[6]  = MC[1].z * L2E_; c0[7]  = MC[1].w * L2E_;                         \
    c0[8]  = MC[2].x * L2E_; c0[9]  = MC[2].y * L2E_;                         \
    c0[10] = MC[2].z * L2E_; c0[11] = MC[2].w * L2E_;                         \
    c0[12] = MC[3].x * L2E_; c0[13] = MC[3].y * L2E_;                         \
    c0[14] = MC[3].z * L2E_; c0[15] = MC[3].w * L2E_;                         \
    c1[0]  = MC[4].x * L2E_; c1[1]  = MC[4].y * L2E_;                         \
    c1[2]  = MC[4].z * L2E_; c1[3]  = MC[4].w * L2E_;                         \
    c1[4]  = MC[5].x * L2E_; c1[5]  = MC[5].y * L2E_;                         \
    c1[6]  = MC[5].z * L2E_; c1[7]  = MC[5].w * L2E_;                         \
    c1[8]  = MC[6].x * L2E_; c1[9]  = MC[6].y * L2E_;                         \
    c1[10] = MC[6].z * L2E_; c1[11] = MC[6].w * L2E_;                         \
    c1[12] = MC[7].x * L2E_; c1[13] = MC[7].y * L2E_;                         \
    c1[14] = MC[7].z * L2E_; c1[15] = MC[7].w * L2E_;                         \
    Frag qf0, qf1, ka0, ka1;                                                  \
    _Pragma("unroll")                                                         \
    for (int t_ = 0; t_ < 4; ++t_) { qf0.i[t_] = bq[t_]; qf1.i[t_] = bq[4 + t_]; } \
    _Pragma("unroll")                                                         \
    for (int t_ = 0; t_ < 4; ++t_) {                                          \
        ka0.i[t_] = k_lds[BF][4 * hi + t_][lq];                               \
        ka1.i[t_] = k_lds[BF][8 + 4 * hi + t_][lq];                           \
    }                                                                         \
    __builtin_amdgcn_s_setprio(1);                                            \
    c0 = MFMA32(ka0.v, qf0.v, c0);                                            \
    c0 = MFMA32(ka1.v, qf1.v, c0);                                            \
    __builtin_amdgcn_s_setprio(0);                                            \
    _Pragma("unroll")                                                         \
    for (int t_ = 0; t_ < 4; ++t_) {                                          \
        ka0.i[t_] = k_lds[BF][4 * hi + t_][32 + lq];                          \
        ka1.i[t_] = k_lds[BF][8 + 4 * hi + t_][32 + lq];                      \
    }                                                                         \
    __builtin_amdgcn_s_setprio(1);                                            \
    c1 = MFMA32(ka0.v, qf0.v, c1);                                            \
    c1 = MFMA32(ka1.v, qf1.v, c1);                                            \
    __builtin_amdgcn_s_setprio(0);                                            \
    float pmax = c0[0];                                                       \
    _Pragma("unroll")                                                         \
    for (int i_ = 1; i_ < 16; ++i_) pmax = fmaxf(pmax, c0[i_]);               \
    _Pragma("unroll")                                                         \
    for (int i_ = 0; i_ < 16; ++i_) pmax = fmaxf(pmax, c1[i_]);               \
    pmax = fmaxf(pmax, __shfl_xor(pmax, 32));                                 \
    if (!__all((int)(pmax <= mrun + 11.5415603f))) {                          \
        const float newm_ = fmaxf(mrun, pmax);                                \
        const float r_ = ex2(mrun - newm_);                                   \
        srun *= r_;                                                           \
        _Pragma("unroll")                                                     \
        for (int i_ = 0; i_ < 16; ++i_) o[i_] *= r_;                          \
        mrun = newm_;                                                         \
    }                                                                         \
    float ls = 0.f;                                                           \
    _Pragma("unroll")                                                         \
    for (int i_ = 0; i_ < 16; ++i_) { c0[i_] = ex2(c0[i_] - mrun); ls += c0[i_]; } \
    _Pragma("unroll")                                                         \
    for (int i_ = 0; i_ < 16; ++i_) { c1[i_] = ex2(c1[i_] - mrun); ls += c1[i_]; } \
    ls += __shfl_xor(ls, 32);                                                 \
    srun += ls;                                                               \
    PVSTEP(BF, c0, 0);                                                        \
    PVSTEP(BF, c1, 1);                                                        \
    } while (0)

    f32x16 o;
#pragma unroll
    for (int i = 0; i < 16; ++i) o[i] = 0.f;
    float mrun = -1e30f, srun = 0.f;
    float4 mc[8], mn[8];

    STAGE(0, kv0);
    MLOAD(mc, kv0);
    __syncthreads();   // drains vmcnt before barrier

    for (int t = 0; t < NT2_; t += 2) {
        const int kk = kv0 + t * KV_;
        STAGE(1, kk + KV_);
        MLOAD(mn, kk + KV_);
        COMPUTE(0, mc);
        __syncthreads();
        if (t + 2 < NT2_) {
            STAGE(0, kk + 2 * KV_);
            MLOAD(mc, kk + 2 * KV_);
        }
        COMPUTE(1, mn);
        __syncthreads();
    }

    // ---- partial epilogue: normalized O (f16) + lse (f32, log2 domain) ----
    const float inv = 1.f / srun;
    const float lse = mrun + lg2(srun);
    unsigned short* pob = po + ((size_t)((sp * B_ + b) * NH_ + h) * HD_) * L_ + qrow;
#pragma unroll
    for (int i = 0; i < 16; ++i) {
        const int d = (i & 3) + 8 * (i >> 2) + 4 * hi;
        if (d < HD_) {
            union { __fp16 hf; unsigned short us; } cv;
            cv.hf = (__fp16)(o[i] * inv);
            pob[(size_t)d * L_] = cv.us;
        }
    }
    if (hi == 0)
        pms[((size_t)(sp * B_ + b) * NH_ + h) * L_ + qrow] = lse;
#undef STAGE
#undef MLOAD
#undef PVSTEP
#undef COMPUTE
}

// ---------------------------------------------------------------------------
// Combine the two KV-split partials: out = sum_i no_i * 2^(l_i-l*) / sum_i 2^(l_i-l*)
// ---------------------------------------------------------------------------
__global__ __launch_bounds__(256) void combine_kernel(const unsigned short* __restrict__ po,
                                                      const float* __restrict__ pms,
                                                      float* __restrict__ att) {
    const int qrow = blockIdx.x * 256 + threadIdx.x;
    const int h    = blockIdx.y;
    const int b    = blockIdx.z;

    const float l0 = pms[((size_t)(0 * B_ + b) * NH_ + h) * L_ + qrow];
    const float l1 = pms[((size_t)(1 * B_ + b) * NH_ + h) * L_ + qrow];
    const float lm = fmaxf(l0, l1);
    const float w0 = ex2(l0 - lm);
    const float w1 = ex2(l1 - lm);
    const float inv = 1.f / (w0 + w1);

    const unsigned short* p0 = po + ((size_t)((0 * B_ + b) * NH_ + h) * HD_) * L_ + qrow;
    const unsigned short* p1 = po + ((size_t)((1 * B_ + b) * NH_ + h) * HD_) * L_ + qrow;
    float* op = att + ((size_t)b * C_ + h * HD_) * L_ + qrow;
#pragma unroll
    for (int d = 0; d < HD_; ++d) {
        union { unsigned short us; __fp16 hf; } a, c;
        a.us = p0[(size_t)d * L_];
        c.us = p1[(size_t)d * L_];
        op[(size_t)d * L_] = ((float)a.hf * w0 + (float)c.hf * w1) * inv;
    }
}

// ---------------------------------------------------------------------------
extern "C" void kernel_launch(void* const* d_in, const int* in_sizes, int n_in,
                              void* d_out, int out_size, void* d_ws, size_t ws_size,
                              hipStream_t stream) {
    const float* x      = (const float*)d_in[0];
    const float* mask   = (const float*)d_in[1];
    const float* w_qkv  = (const float*)d_in[2];
    const float* b_qkv  = (const float*)d_in[3];
    const float* w_proj = (const float*)d_in[4];
    const float* b_proj = (const float*)d_in[5];
    float* out = (float*)d_out;

    unsigned int*   q2  = (unsigned int*)d_ws;                              // B*8*12*L u32
    unsigned int*   k2  = q2 + (size_t)B_ * NH_ * 12 * L_;                  // B*8*12*L u32
    unsigned short* v16 = (unsigned short*)(k2 + (size_t)B_ * NH_ * 12 * L_); // B*8*24*L u16
    unsigned short* po  = v16 + (size_t)B_ * NH_ * HD_ * L_;                // 2*B*8*24*L u16
    float* pms    = (float*)(po + (size_t)NSPL_ * B_ * NH_ * HD_ * L_);     // 2*B*8*L f32
    float* ws_att = pms + (size_t)NSPL_ * B_ * NH_ * L_;                    // B*192*L f32

    lin_qkv<<<dim3(72, 32), 256, 0, stream>>>(x, w_qkv, b_qkv, q2, k2, v16);
    attn_mfma<<<dim3(512 * NSPL_), 256, 0, stream>>>(q2, k2, v16, mask, po, pms);
    combine_kernel<<<dim3(16, NH_, B_), 256, 0, stream>>>(po, pms, ws_att);
    lin_kernel<<<dim3(24, 32), 256, 0, stream>>>(ws_att, w_proj, b_proj, out, C_);
}